// Round 3
// baseline (217.158 us; speedup 1.0000x reference)
//
#include <hip/hip_runtime.h>

// Problem constants
#define N_ROWS 131072    // 32*4096
#define D 64
#define K_CODES 1024
#define MT 2             // 16-row M-tiles per wave
#define ROWS_PER_BLOCK 128   // 4 waves * MT*16
#define NCHUNK (K_CODES / 64)

typedef _Float16 f16x8 __attribute__((ext_vector_type(8)));
typedef float    f32x4 __attribute__((ext_vector_type(4)));

// ---------------------------------------------------------------------------
// K0: prep — per-code |c|^2, fp32->f16 hi/lo split codebook, zero loss.
// CBs layout: [code][0..63]=hi, [64..127]=lo  (f16), 256 KB total.
// ---------------------------------------------------------------------------
__global__ __launch_bounds__(256)
void prep_kernel(const float* __restrict__ CB, _Float16* __restrict__ CBs,
                 float* __restrict__ csqr, float* __restrict__ loss) {
    int k = blockIdx.x * 256 + threadIdx.x;   // grid 4*256 = 1024
    if (k == 0) *loss = 0.0f;
    if (k >= K_CODES) return;
    const float4* p = (const float4*)(CB + (size_t)k * D);
    _Float16* hi = CBs + (size_t)k * 128;
    _Float16* lo = hi + 64;
    float s = 0.0f;
#pragma unroll
    for (int i = 0; i < 16; ++i) {
        float4 v = p[i];
        s += v.x * v.x + v.y * v.y + v.z * v.z + v.w * v.w;
        float vv[4] = {v.x, v.y, v.z, v.w};
#pragma unroll
        for (int j = 0; j < 4; ++j) {
            _Float16 h = (_Float16)vv[j];
            hi[i * 4 + j] = h;
            lo[i * 4 + j] = (_Float16)(vv[j] - (float)h);
        }
    }
    csqr[k] = s;
}

// ---------------------------------------------------------------------------
// K1: fused split-f16 MFMA argmin + z_q gather + loss.
// Wave owns 32 rows (MT=2 tiles of 16). A = (-2x) as f16 hi+lo in regs.
// B = pre-split codebook chunk (64 codes) staged to LDS by pure b128 copy,
// register-prefetched one chunk ahead. score = |c|^2 + (-2x)·c via acc-init
// = csqr and 6 MFMAs (hh, lh, hl passes over two K-halves).
// loss uses sum(x^2) + sum(s_best) == sum((x-q)^2).
// ---------------------------------------------------------------------------
__global__ __launch_bounds__(256, 4)
void argmin_kernel(const float* __restrict__ X,
                   const _Float16* __restrict__ CBs,
                   const float* __restrict__ csqr,
                   const float* __restrict__ CB,
                   float* __restrict__ zq, float* __restrict__ idxf,
                   float* __restrict__ loss) {
    // [code][k]: 0..63 hi, 64..127 lo, pad to 136 halves (272 B row stride:
    // 16B-aligned; frag reads land 8 word-accesses/bank = structural min).
    __shared__ __align__(16) _Float16 Bs[64][136];
    __shared__ float LsC[K_CODES];   // csqr copy (4 KB)

    const int t    = threadIdx.x;
    const int wave = t >> 6;
    const int lane = t & 63;
    const int lrow = lane & 15;   // A row-in-tile / B+D column (code slot)
    const int quad = lane >> 4;
    const int R0   = blockIdx.x * ROWS_PER_BLOCK + wave * (MT * 16);

    // ---- A fragments: xs = -2x split hi/lo; accumulate sum(x^2) on the fly.
    // MFMA A layout: lane holds A[m=lane&15][k=quad*8+j], j=0..7.
    f16x8 Ah[MT][2], Al[MT][2];
    float xsq = 0.0f;
#pragma unroll
    for (int mt = 0; mt < MT; ++mt) {
        const float* xr = X + (size_t)(R0 + mt * 16 + lrow) * D;
#pragma unroll
        for (int ks = 0; ks < 2; ++ks) {
            const int k0 = ks * 32 + quad * 8;
            float4 v0 = *(const float4*)(xr + k0);
            float4 v1 = *(const float4*)(xr + k0 + 4);
            float xs[8] = {v0.x, v0.y, v0.z, v0.w, v1.x, v1.y, v1.z, v1.w};
            f16x8 h, l;
#pragma unroll
            for (int j = 0; j < 8; ++j) {
                xsq += xs[j] * xs[j];
                float sv = -2.0f * xs[j];
                _Float16 hh = (_Float16)sv;
                h[j] = hh;
                l[j] = (_Float16)(sv - (float)hh);
            }
            Ah[mt][ks] = h;
            Al[mt][ks] = l;
        }
    }

    // Stage csqr into LDS (one float4 per thread; visible after 1st barrier).
    ((float4*)LsC)[t] = ((const float4*)csqr)[t];

    float bestd[MT][4];
    int   besti[MT][4];
#pragma unroll
    for (int mt = 0; mt < MT; ++mt)
#pragma unroll
        for (int r = 0; r < 4; ++r) { bestd[mt][r] = 3.0e38f; besti[mt][r] = 0; }

    // Register-prefetch chunk 0 (16 KB/chunk, 4 f16x8 units per thread).
    const f16x8* gB = (const f16x8*)CBs;   // 16 units per code
    f16x8 pf[4];
#pragma unroll
    for (int i = 0; i < 4; ++i) pf[i] = gB[i * 256 + t];

    for (int chunk = 0; chunk < NCHUNK; ++chunk) {
        // Write prefetched chunk to LDS (pure copy, no conversion).
#pragma unroll
        for (int i = 0; i < 4; ++i) {
            int q = i * 256 + t, code = q >> 4, u = q & 15;
            *(f16x8*)&Bs[code][u * 8] = pf[i];
        }
        __syncthreads();
        // Prefetch next chunk while computing this one.
        if (chunk + 1 < NCHUNK) {
#pragma unroll
            for (int i = 0; i < 4; ++i)
                pf[i] = gB[(chunk + 1) * 1024 + i * 256 + t];
        }

#pragma unroll
        for (int ct = 0; ct < 4; ++ct) {
            // B layout: lane holds B[k=quad*8+j][n=lane&15].
            const _Float16* bp = &Bs[ct * 16 + lrow][quad * 8];
            f16x8 Bh0 = *(const f16x8*)(bp);
            f16x8 Bh1 = *(const f16x8*)(bp + 32);
            f16x8 Bl0 = *(const f16x8*)(bp + 64);
            f16x8 Bl1 = *(const f16x8*)(bp + 96);
            const int   c  = chunk * 64 + ct * 16 + lrow;
            const float cs = LsC[c];
#pragma unroll
            for (int mt = 0; mt < MT; ++mt) {
                f32x4 acc = {cs, cs, cs, cs};   // score = |c|^2 + (-2x)·c
                acc = __builtin_amdgcn_mfma_f32_16x16x32_f16(Ah[mt][0], Bh0, acc, 0, 0, 0);
                acc = __builtin_amdgcn_mfma_f32_16x16x32_f16(Ah[mt][1], Bh1, acc, 0, 0, 0);
                acc = __builtin_amdgcn_mfma_f32_16x16x32_f16(Al[mt][0], Bh0, acc, 0, 0, 0);
                acc = __builtin_amdgcn_mfma_f32_16x16x32_f16(Al[mt][1], Bh1, acc, 0, 0, 0);
                acc = __builtin_amdgcn_mfma_f32_16x16x32_f16(Ah[mt][0], Bl0, acc, 0, 0, 0);
                acc = __builtin_amdgcn_mfma_f32_16x16x32_f16(Ah[mt][1], Bl1, acc, 0, 0, 0);
                // Codes ascend with (chunk, ct) for fixed lane -> strict <
                // keeps first minimum (np.argmin semantics).
#pragma unroll
                for (int r = 0; r < 4; ++r) {
                    bool lt = acc[r] < bestd[mt][r];
                    bestd[mt][r] = lt ? acc[r] : bestd[mt][r];
                    besti[mt][r] = lt ? c : besti[mt][r];
                }
            }
        }
        __syncthreads();
    }

    const float scale = 1.25f / (float)((size_t)N_ROWS * D);

    // sum(x^2) over this wave's 32 rows (each element counted exactly once).
#pragma unroll
    for (int m = 1; m < 64; m <<= 1) xsq += __shfl_xor(xsq, m, 64);
    if (lane == 0) atomicAdd(loss, xsq * scale);

    // Argmin reduce across 16 code-columns (lexicographic on ties), then
    // write idxf, gather z_q row, and accumulate sum(s_best).
    float ssum = 0.0f;
#pragma unroll
    for (int mt = 0; mt < MT; ++mt) {
#pragma unroll
        for (int r = 0; r < 4; ++r) {
            float dv = bestd[mt][r];
            int   iv = besti[mt][r];
#pragma unroll
            for (int m = 1; m < 16; m <<= 1) {
                float od = __shfl_xor(dv, m, 64);
                int   oi = __shfl_xor(iv, m, 64);
                if (od < dv || (od == dv && oi < iv)) { dv = od; iv = oi; }
            }
            // All 16 lanes of this quad-group now agree on (dv, iv).
            int row = R0 + mt * 16 + quad * 4 + r;
            if (lrow == 0) {
                idxf[row] = (float)iv;
                ssum += dv;
            }
            float4 cv = *(const float4*)(CB + (size_t)iv * D + lrow * 4);
            *(float4*)(zq + (size_t)row * D + lrow * 4) = cv;
        }
    }
    // ssum lives at lanes 0,16,32,48; fold across quads, one atomic per wave.
    ssum += __shfl_xor(ssum, 16, 64);
    ssum += __shfl_xor(ssum, 32, 64);
    if (lane == 0) atomicAdd(loss, ssum * scale);
}

// ---------------------------------------------------------------------------
extern "C" void kernel_launch(void* const* d_in, const int* in_sizes, int n_in,
                              void* d_out, int out_size, void* d_ws,
                              size_t ws_size, hipStream_t stream) {
    const float* X  = (const float*)d_in[0];   // inputs  [131072,64]
    const float* CB = (const float*)d_in[1];   // codebook [1024,64]

    float* out  = (float*)d_out;
    float* loss = out;                                   // [0]
    float* zq   = out + 1;                               // [1 .. 8388608]
    float* idxf = out + 1 + (size_t)N_ROWS * D;          // indices as float

    float*    csqr = (float*)d_ws;                       // 1024 floats
    _Float16* CBs  = (_Float16*)((char*)d_ws + 4096);    // 256 KB split CB

    hipLaunchKernelGGL(prep_kernel, dim3(4), dim3(256), 0, stream,
                       CB, CBs, csqr, loss);
    hipLaunchKernelGGL(argmin_kernel, dim3(N_ROWS / ROWS_PER_BLOCK), dim3(256),
                       0, stream, X, CBs, csqr, CB, zq, idxf, loss);
}

// Round 4
// 165.550 us; speedup vs baseline: 1.3117x; 1.3117x over previous
//
#include <hip/hip_runtime.h>

// Problem constants
#define N_ROWS 131072    // 32*4096
#define D 64
#define K_CODES 1024
#define NTILE 64         // 16-code tiles

typedef _Float16 f16x8 __attribute__((ext_vector_type(8)));
typedef float    f32x4 __attribute__((ext_vector_type(4)));

#define MFMA16(a, b, c) __builtin_amdgcn_mfma_f32_16x16x32_f16((a), (b), (c), 0, 0, 0)

// ---------------------------------------------------------------------------
// ws layout: csqr[1024] f32 (4 KB) | CBf: 16384 f16x8 units (256 KB) + 8 KB pad
// CBf unit index = tile*256 + f*64 + lane, f in {0:hi k0-31, 1:hi k32-63,
// 2:lo k0-31, 3:lo k32-63}; unit holds the 8 halves lane needs for that
// MFMA B fragment: B[k = (lane>>4)*8 + j][n = lane&15], code = tile*16 + n.
// => argmin's B loads are single coalesced 16B reads, no LDS, no barriers.
// ---------------------------------------------------------------------------
__global__ __launch_bounds__(256)
void prep_kernel(const float* __restrict__ CB, _Float16* __restrict__ CBf,
                 float* __restrict__ csqr, float* __restrict__ loss) {
    const int b = blockIdx.x, t = threadIdx.x;
    if (b < 64) {
        const int unit = b * 256 + t;
        const int tile = unit >> 8;
        const int f    = (unit >> 6) & 3;
        const int lane = unit & 63;
        const int quad = lane >> 4, lrow = lane & 15;
        const int code = tile * 16 + lrow;
        const int k0   = (f & 1) * 32 + quad * 8;
        const float* src = CB + (size_t)code * D + k0;
        float4 v0 = *(const float4*)(src);
        float4 v1 = *(const float4*)(src + 4);
        float xs[8] = {v0.x, v0.y, v0.z, v0.w, v1.x, v1.y, v1.z, v1.w};
        f16x8 o;
#pragma unroll
        for (int j = 0; j < 8; ++j) {
            _Float16 h = (_Float16)xs[j];
            o[j] = (f < 2) ? h : (_Float16)(xs[j] - (float)h);
        }
        *(f16x8*)(CBf + (size_t)unit * 8) = o;
    } else {
        if (t == 0) *loss = 0.0f;
        for (int k = t; k < K_CODES; k += 256) {
            const float4* p = (const float4*)(CB + (size_t)k * D);
            float s = 0.0f;
#pragma unroll
            for (int i = 0; i < 16; ++i) {
                float4 v = p[i];
                s += v.x * v.x + v.y * v.y + v.z * v.z + v.w * v.w;
            }
            csqr[k] = s;
        }
    }
}

// ---------------------------------------------------------------------------
// K1: barrier-free split-f16 MFMA argmin + fused z_q gather + loss.
// Wave owns 64 rows (MT=4). A = (-2x) hi/lo in regs. B streamed from the
// fragment-ordered CBf through L1/L2 with register double-buffering
// (distance-1 prefetch). score = |c|^2 + (-2x)·c, acc-init = csqr, 6 MFMAs
// (hh,lh,hl over two K-halves; ll term ~2^-24, dropped).
// loss = 1.25/ND * (sum x^2 + sum s_best). zq stores 16B-aligned despite the
// out+1 offset (lane 15 covers the 3 head + 1 tail dwords of each row).
// ---------------------------------------------------------------------------
__global__ __launch_bounds__(256, 3)
void argmin_kernel(const float* __restrict__ X,
                   const _Float16* __restrict__ CBf,
                   const float* __restrict__ csqr,
                   const float* __restrict__ CB,
                   float* __restrict__ out) {
    __shared__ float LsC[K_CODES];   // csqr copy, 4 KB (only LDS use)

    const int t    = threadIdx.x;
    const int wave = t >> 6;
    const int lane = t & 63;
    const int lrow = lane & 15;
    const int quad = lane >> 4;
    const int R0   = blockIdx.x * 256 + wave * 64;

    float* const zq   = out + 1;
    float* const idxf = out + 1 + (size_t)N_ROWS * D;

    // Stage csqr to LDS (barrier below overlaps the A global-load latency).
    ((float4*)LsC)[t] = ((const float4*)csqr)[t];

    // ---- A fragments: (-2x) split hi/lo; accumulate sum(x^2) on the fly.
    // A layout: lane holds A[m=lane&15][k=quad*8+j], j=0..7.
    f16x8 Ah[4][2], Al[4][2];
    float xsq = 0.0f;
#pragma unroll
    for (int mt = 0; mt < 4; ++mt) {
        const float* xr = X + (size_t)(R0 + mt * 16 + lrow) * D;
#pragma unroll
        for (int ks = 0; ks < 2; ++ks) {
            const int k0 = ks * 32 + quad * 8;
            float4 v0 = *(const float4*)(xr + k0);
            float4 v1 = *(const float4*)(xr + k0 + 4);
            float xs[8] = {v0.x, v0.y, v0.z, v0.w, v1.x, v1.y, v1.z, v1.w};
            f16x8 h, l;
#pragma unroll
            for (int j = 0; j < 8; ++j) {
                xsq += xs[j] * xs[j];
                float sv = -2.0f * xs[j];
                _Float16 hh = (_Float16)sv;
                h[j] = hh;
                l[j] = (_Float16)(sv - (float)hh);
            }
            Ah[mt][ks] = h;
            Al[mt][ks] = l;
        }
    }
    __syncthreads();   // LsC ready (the only barrier in the kernel)

    float bestd[4][4];
    int   besti[4][4];
#pragma unroll
    for (int mt = 0; mt < 4; ++mt)
#pragma unroll
        for (int r = 0; r < 4; ++r) { bestd[mt][r] = 3.0e38f; besti[mt][r] = 0; }

    const f16x8* gw = (const f16x8*)CBf + lane;   // + tile*256 + f*64

#define LOADB(Bv, tl)                                                         \
    do {                                                                      \
        const f16x8* _p = gw + (tl) * 256;                                    \
        Bv[0] = _p[0]; Bv[1] = _p[64]; Bv[2] = _p[128]; Bv[3] = _p[192];      \
    } while (0)

#define COMPUTE(Bv, tl)                                                       \
    do {                                                                      \
        const float cs = LsC[(tl) * 16 + lrow];                               \
        const int   c  = (tl) * 16 + lrow;                                    \
        _Pragma("unroll")                                                     \
        for (int mt = 0; mt < 4; ++mt) {                                      \
            f32x4 acc = {cs, cs, cs, cs};                                     \
            acc = MFMA16(Ah[mt][0], Bv[0], acc);                              \
            acc = MFMA16(Ah[mt][1], Bv[1], acc);                              \
            acc = MFMA16(Al[mt][0], Bv[0], acc);                              \
            acc = MFMA16(Al[mt][1], Bv[1], acc);                              \
            acc = MFMA16(Ah[mt][0], Bv[2], acc);                              \
            acc = MFMA16(Ah[mt][1], Bv[3], acc);                              \
            _Pragma("unroll")                                                 \
            for (int r = 0; r < 4; ++r) {                                     \
                bool lt = acc[r] < bestd[mt][r];                              \
                bestd[mt][r] = lt ? acc[r] : bestd[mt][r];                    \
                besti[mt][r] = lt ? c : besti[mt][r];                         \
            }                                                                 \
        }                                                                     \
    } while (0)

    // Register double-buffer, two tiles per iteration (no reg-copy shuffle).
    // Codes ascend with tile for fixed lane -> strict < keeps first minimum.
    f16x8 Ba[4], Bb[4];
    LOADB(Ba, 0);
    for (int tile = 0; tile < NTILE; tile += 2) {
        LOADB(Bb, tile + 1);        // tile 64 read lands in the ws pad
        COMPUTE(Ba, tile);
        LOADB(Ba, tile + 2);        // tile 65 read lands in the ws pad
        COMPUTE(Bb, tile + 1);
    }

    const float scale = 1.25f / (float)((size_t)N_ROWS * D);

    // sum(x^2) over this wave's 64 rows (each element counted exactly once).
#pragma unroll
    for (int m = 1; m < 64; m <<= 1) xsq += __shfl_xor(xsq, m, 64);

    // Argmin reduce across the 16 code-columns (lexicographic on exact ties
    // to keep np.argmin first-min semantics), then fused z_q gather + loss.
    float ssum = 0.0f;
#pragma unroll
    for (int mt = 0; mt < 4; ++mt) {
#pragma unroll
        for (int r = 0; r < 4; ++r) {
            float dv = bestd[mt][r];
            int   iv = besti[mt][r];
#pragma unroll
            for (int m = 1; m < 16; m <<= 1) {
                float od = __shfl_xor(dv, m, 64);
                int   oi = __shfl_xor(iv, m, 64);
                if (od < dv || (od == dv && oi < iv)) { dv = od; iv = oi; }
            }
            // All 16 lanes of this quad-group agree on (dv, iv).
            const int    row = R0 + mt * 16 + quad * 4 + r;
            const float* cr  = CB + (size_t)iv * D;
            float*       zr  = zq + (size_t)row * D;
            if (lrow < 15) {
                // elements 3+4*lrow .. 6+4*lrow ; store is 16B-aligned
                // ((out+1)+3 = out+4).
                const int e = 3 + 4 * lrow;
                float4 cv = make_float4(cr[e], cr[e + 1], cr[e + 2], cr[e + 3]);
                *(float4*)(zr + e) = cv;
            } else {
                zr[0]  = cr[0];
                zr[1]  = cr[1];
                zr[2]  = cr[2];
                zr[63] = cr[63];
            }
            if (lrow == 0) {
                idxf[row] = (float)iv;
                ssum += dv;   // s_best = |c|^2 - 2x·c ; sum x^2 added below
            }
        }
    }
    // ssum lives at lanes 0,16,32,48; fold across quads, one atomic per wave.
    ssum += __shfl_xor(ssum, 16, 64);
    ssum += __shfl_xor(ssum, 32, 64);
    if (lane == 0) atomicAdd(out, (xsq + ssum) * scale);
}

// ---------------------------------------------------------------------------
extern "C" void kernel_launch(void* const* d_in, const int* in_sizes, int n_in,
                              void* d_out, int out_size, void* d_ws,
                              size_t ws_size, hipStream_t stream) {
    const float* X  = (const float*)d_in[0];   // inputs  [131072,64]
    const float* CB = (const float*)d_in[1];   // codebook [1024,64]

    float*    csqr = (float*)d_ws;                      // 4 KB
    _Float16* CBf  = (_Float16*)((char*)d_ws + 4096);   // 256 KB + 8 KB pad

    hipLaunchKernelGGL(prep_kernel, dim3(65), dim3(256), 0, stream,
                       CB, CBf, csqr, (float*)d_out);
    hipLaunchKernelGGL(argmin_kernel, dim3(N_ROWS / 256), dim3(256), 0, stream,
                       X, CBf, csqr, CB, (float*)d_out);
}